// Round 1
// 312.361 us; speedup vs baseline: 1.0419x; 1.0419x over previous
//
#include <hip/hip_runtime.h>

#define KSIZE 7
#define SR    2
#define SAMP  (KSIZE * SR)   // 14 sample coords per axis
#define NBINS (KSIZE * KSIZE)
#define NMAX  4096
#define BMAX  8

typedef float v4f __attribute__((ext_vector_type(4)));

// Problem-fixed geometry (asserted by launcher): H=W=64, C=256.
constexpr int C4c  = 64;     // C/4   (v4f units per pixel)
constexpr int WC4c = 4096;   // W*C4  (v4f units per row)

// ---------------------------------------------------------------------------
// One-block bucketing: builds assign[bb] = roi index, such that bb % B ==
// batch of that roi wherever possible (blocks round-robin across the 8 XCDs,
// so bucket k lands on XCD k -> per-XCD L2 holds exactly one image).
// All coordination in LDS; zero global atomics.
// ---------------------------------------------------------------------------
__global__ __launch_bounds__(256) void bucket_kernel(
    const int* __restrict__ bi, int* __restrict__ assign, int N, int B, int cap)
{
    __shared__ int cnt[BMAX];
    __shared__ int ovf_n, ovf_c;
    __shared__ int asg[NMAX];
    __shared__ int ovf[NMAX];

    const int t = threadIdx.x;
    if (t < BMAX) cnt[t] = 0;
    if (t == 0) { ovf_n = 0; ovf_c = 0; }
    for (int i = t; i < N; i += 256) asg[i] = -1;
    __syncthreads();

    for (int i = t; i < N; i += 256) {
        int k = bi[i];
        int p = atomicAdd(&cnt[k], 1);           // LDS atomic: cheap
        if (p < cap) asg[p * B + k] = i;         // primary slot on XCD k
        else { int q = atomicAdd(&ovf_n, 1); ovf[q] = i; }
    }
    __syncthreads();

    for (int i = t; i < N; i += 256) {           // fill holes from overflow
        if (asg[i] < 0) { int q = atomicAdd(&ovf_c, 1); asg[i] = ovf[q]; }
    }
    __syncthreads();

    for (int i = t; i < N; i += 256) assign[i] = asg[i];
}

// ---------------------------------------------------------------------------
// Per-bin helpers. All V[] indices are compile-time constants after inlining
// (rule: runtime-indexed register arrays go to scratch).
// ---------------------------------------------------------------------------
__device__ __forceinline__ void issue_bin(
    v4f (&V)[16], int bin, const v4f* __restrict__ xbase,
    const int* y0s, const int* x0s)
{
    const int ky  = bin / KSIZE;
    const int kx  = bin - ky * KSIZE;
    const int ya0 = y0s[ky * SR], ya1 = y0s[ky * SR + 1];
    const int xa0 = x0s[kx * SR], xa1 = x0s[kx * SR + 1];
    const v4f* q0 = xbase + ya0 * WC4c + xa0 * C4c;   // sample (0,0)
    const v4f* q1 = xbase + ya0 * WC4c + xa1 * C4c;   // sample (0,1)
    const v4f* q2 = xbase + ya1 * WC4c + xa0 * C4c;   // sample (1,0)
    const v4f* q3 = xbase + ya1 * WC4c + xa1 * C4c;   // sample (1,1)
    V[0]  = q0[0]; V[1]  = q0[C4c]; V[2]  = q0[WC4c]; V[3]  = q0[WC4c + C4c];
    V[4]  = q1[0]; V[5]  = q1[C4c]; V[6]  = q1[WC4c]; V[7]  = q1[WC4c + C4c];
    V[8]  = q2[0]; V[9]  = q2[C4c]; V[10] = q2[WC4c]; V[11] = q2[WC4c + C4c];
    V[12] = q3[0]; V[13] = q3[C4c]; V[14] = q3[WC4c]; V[15] = q3[WC4c + C4c];
}

__device__ __forceinline__ void compute_bin(
    const v4f (&V)[16], int bin, float* __restrict__ outn, int lane,
    const float* lys, const float* lxs)
{
    const int ky = bin / KSIZE;
    const int kx = bin - ky * KSIZE;
    v4f acc = {0.f, 0.f, 0.f, 0.f};
    #pragma unroll
    for (int s = 0; s < 4; ++s) {
        const float ly  = lys[ky * SR + (s >> 1)];
        const float lx  = lxs[kx * SR + (s & 1)];
        const float w00 = (1.f - ly) * (1.f - lx);
        const float w01 = (1.f - ly) * lx;
        const float w10 = ly * (1.f - lx);
        const float w11 = ly * lx;
        acc += V[4*s+0]*w00 + V[4*s+1]*w01 + V[4*s+2]*w10 + V[4*s+3]*w11;
    }
    acc *= 0.25f;
    v4f* op = (v4f*)(outn + (size_t)bin * 256) + lane;
    __builtin_nontemporal_store(acc, op);     // write-once stream
}

// ---------------------------------------------------------------------------
// Main kernel: one block per ROI; wave w handles bins w, w+4, ...
// lane = channel group (64 lanes x float4 = 256 channels, fully coalesced).
//
// R2 experiment: 2-deep software pipeline. The old loop issued 16 loads,
// then the FMA phase drained vmcnt to 0 before the next bin's loads — avg
// outstanding ~8KB/wave, Little's-law-starving the L2 path (measured 22.7
// TB/s of the 34.5 TB/s ceiling). Ping-pong register sets vA/vB keep ~32
// loads (32KB) in flight per wave. VGPR grows to ~160 (occupancy 3/SIMD);
// that trade is intentional: 12 waves x 24KB outstanding >> 19 x 8KB.
// ---------------------------------------------------------------------------
__global__ __launch_bounds__(256, 3) void roialign_kernel(
    const float* __restrict__ x,         // [B,H,W,C]
    const float* __restrict__ rois,      // [N,4] (y1,x1,y2,x2)
    const int*   __restrict__ batch_idx, // [N]
    float*       __restrict__ out,       // [N,K,K,C]
    const int*   __restrict__ assign,
    int H, int W, int C)
{
    __shared__ int   sh_n;
    __shared__ int   y0s[SAMP];
    __shared__ float lys[SAMP];
    __shared__ int   x0s[SAMP];
    __shared__ float lxs[SAMP];

    const int t = threadIdx.x;
    if (t == 0) sh_n = assign[blockIdx.x];
    __syncthreads();
    const int n = sh_n;

    const float4 rb = ((const float4*)rois)[n];   // (y1,x1,y2,x2) broadcast
    const float bin_h = (rb.z - rb.x) / (float)KSIZE;
    const float bin_w = (rb.w - rb.y) / (float)KSIZE;

    if (t < SAMP) {
        const float off = ((float)t + 0.5f) / (float)SR;
        const float sy  = rb.x + off * bin_h;
        float fy = floorf(sy);
        fy = fminf(fmaxf(fy, 0.0f), (float)(H - 2));
        y0s[t] = (int)fy;
        lys[t] = fminf(fmaxf(sy - fy, 0.0f), 1.0f);
    } else if (t < 2 * SAMP) {
        const int s = t - SAMP;
        const float off = ((float)s + 0.5f) / (float)SR;
        const float sx  = rb.y + off * bin_w;
        float fx = floorf(sx);
        fx = fminf(fmaxf(fx, 0.0f), (float)(W - 2));
        x0s[s] = (int)fx;
        lxs[s] = fminf(fmaxf(sx - fx, 0.0f), 1.0f);
    }
    __syncthreads();

    const int bimg = batch_idx[n];
    const int lane = t & 63;
    const int wave = t >> 6;

    const v4f* __restrict__ xbase =
        (const v4f*)x + (size_t)bimg * 64 * WC4c + lane;
    float* __restrict__ outn = out + (size_t)n * NBINS * 256;

    v4f vA[16], vB[16];

    int bin = wave;                 // wave < 4 <= NBINS, so always valid
    issue_bin(vA, bin, xbase, y0s, x0s);
    for (;;) {
        int nb = bin + 4;
        if (nb < NBINS) {
            issue_bin(vB, nb, xbase, y0s, x0s);       // prefetch next
            compute_bin(vA, bin, outn, lane, lys, lxs);
            bin = nb;
        } else {
            compute_bin(vA, bin, outn, lane, lys, lxs);
            break;
        }
        nb = bin + 4;
        if (nb < NBINS) {
            issue_bin(vA, nb, xbase, y0s, x0s);       // prefetch next
            compute_bin(vB, bin, outn, lane, lys, lxs);
            bin = nb;
        } else {
            compute_bin(vB, bin, outn, lane, lys, lxs);
            break;
        }
    }
}

extern "C" void kernel_launch(void* const* d_in, const int* in_sizes, int n_in,
                              void* d_out, int out_size, void* d_ws, size_t ws_size,
                              hipStream_t stream) {
    const float* x         = (const float*)d_in[0];
    const float* rois      = (const float*)d_in[1];
    const int*   batch_idx = (const int*)d_in[2];
    float*       out       = (float*)d_out;
    int*         assign    = (int*)d_ws;

    const int H = 64, W = 64, C = 256;
    const int N = in_sizes[1] / 4;                 // rois is [N,4]
    const int B = in_sizes[0] / (H * W * C);       // 8
    const int cap = N / B;                         // 512

    bucket_kernel<<<1, 256, 0, stream>>>(batch_idx, assign, N, B, cap);
    roialign_kernel<<<N, 256, 0, stream>>>(x, rois, batch_idx, out, assign,
                                           H, W, C);
}